// Round 15
// baseline (204.487 us; speedup 1.0000x reference)
//
#include <hip/hip_runtime.h>
#include <cstdint>
#include <cstddef>

typedef __attribute__((ext_vector_type(8))) short bf16x8;
typedef __attribute__((ext_vector_type(4))) float f32x4;
typedef __attribute__((ext_vector_type(16))) float f32x16;
typedef unsigned short ushort_t;

#define MFMA_BF16(a, b, c) __builtin_amdgcn_mfma_f32_16x16x32_bf16((a), (b), (c), 0, 0, 0)
#define MFMA32_BF16(a, b, c) __builtin_amdgcn_mfma_f32_32x32x16_bf16((a), (b), (c), 0, 0, 0)

__device__ __forceinline__ unsigned short f2bf(float f) {
  unsigned int u = __float_as_uint(f);
  u += 0x7fffu + ((u >> 16) & 1u);           // round-to-nearest-even
  return (unsigned short)(u >> 16);
}
__device__ __forceinline__ float bf2f(unsigned short h) {
  return __uint_as_float(((unsigned int)h) << 16);
}
// single-instruction 2^x (v_exp_f32 IS 2^x on CDNA)
__device__ __forceinline__ float exp2_fast(float x) {
  float r;
  asm("v_exp_f32 %0, %1" : "=v"(r) : "v"(x));
  return r;
}
// T12: packed f32x2 -> bf16x2 (lo = src0, hi = src1); no builtin on gfx950
__device__ __forceinline__ uint32_t cvtpk_bf16(float lo, float hi) {
  uint32_t r;
  asm("v_cvt_pk_bf16_f32 %0, %1, %2" : "=v"(r) : "v"(lo), "v"(hi));
  return r;
}

__device__ __forceinline__ void gload_lds16(const void* g, void* lds) {
  __builtin_amdgcn_global_load_lds(
      (const __attribute__((address_space(1))) void*)g,
      (__attribute__((address_space(3))) void*)lds, 16, 0, 0);
}

// ---------------------------------------------------------------- convert
__global__ __launch_bounds__(256)
void cvt_kernel(const float* __restrict__ x, const float* __restrict__ wq,
                const float* __restrict__ wk, const float* __restrict__ wv,
                const float* __restrict__ wo,
                ushort_t* __restrict__ xb, ushort_t* __restrict__ wqb,
                ushort_t* __restrict__ wkb, ushort_t* __restrict__ wvb,
                ushort_t* __restrict__ wob) {
  const float* src; ushort_t* dst; int n;
  switch (blockIdx.y) {
    case 0:  src = x;  dst = xb;  n = 8388608; break;
    case 1:  src = wq; dst = wqb; n = 4194304; break;
    case 2:  src = wk; dst = wkb; n = 1048576; break;
    case 3:  src = wv; dst = wvb; n = 1048576; break;
    default: src = wo; dst = wob; n = 4194304; break;
  }
  const int i = (int)(blockIdx.x * 256u + threadIdx.x) * 4;
  if (i >= n) return;
  const float4 v = *(const float4*)(src + i);
  union { unsigned short us[4]; unsigned long long u64; } pk;
  pk.us[0] = f2bf(v.x); pk.us[1] = f2bf(v.y);
  pk.us[2] = f2bf(v.z); pk.us[3] = f2bf(v.w);
  *(unsigned long long*)(dst + i) = pk.u64;
}

// ---------------------------------------------------------------- fused QKV GEMM
// BK=64, T3 minimal 2-phase drain0. blockIdx.y: 0..15 Q, 16..19 K, 20..23 V^T.
// K-mode epilogue: head-indexed RoPE fused (verified r14). NEW: the 32 (cos,sin)
// pairs are block-uniform -> computed ONCE by threads 0..31 into a 256B LDS
// table (was 32 sincosf PER THREAD = the dominant K-block epilogue cost).
__global__ __launch_bounds__(256, 2)
void gemm_qkv(const ushort_t* __restrict__ A,
              const ushort_t* __restrict__ WQ, const ushort_t* __restrict__ WK,
              const ushort_t* __restrict__ WV,
              ushort_t* __restrict__ Qb, ushort_t* __restrict__ Kb,
              ushort_t* __restrict__ Vtb) {
  __shared__ bf16x8 smem_v[4096];            // 64 KB
  __shared__ float2 trigT[32];               // K-RoPE table (256 B)
  char* smem = (char*)smem_v;
  const int tid  = threadIdx.x;
  const int lane = tid & 63;
  const int wave = tid >> 6;
  const int wr = wave >> 1, wc = wave & 1;
  const int y = blockIdx.y;
  int mode, ylocal;
  const ushort_t* Bsel;
  if (y < 16)      { mode = 0; ylocal = y;      Bsel = WQ; }
  else if (y < 20) { mode = 1; ylocal = y - 16; Bsel = WK; }
  else             { mode = 2; ylocal = y - 20; Bsel = WV; }
  const ushort_t* Abase = A + (size_t)blockIdx.x * 128 * 2048;
  const ushort_t* Bbase = Bsel + (size_t)ylocal * 128 * 2048;

  f32x4 acc[4][4] = {};

  #pragma unroll
  for (int it = 0; it < 4; ++it) {
    const int chunk = it * 4 + wave;
    const int r  = chunk * 8 + (lane >> 3);
    const int cg = (lane & 7) ^ (r & 7);
    gload_lds16(Abase + (size_t)r * 2048 + cg * 8, smem + chunk * 1024);
    gload_lds16(Bbase + (size_t)r * 2048 + cg * 8, smem + 16384 + chunk * 1024);
  }
  __syncthreads();

  for (int t = 0; t < 32; ++t) {
    if (t + 1 < 32) {                        // issue next stage first
      char* dst = smem + ((t + 1) & 1) * 32768;
      const int k0 = (t + 1) * 64;
      #pragma unroll
      for (int it = 0; it < 4; ++it) {
        const int chunk = it * 4 + wave;
        const int r  = chunk * 8 + (lane >> 3);
        const int cg = (lane & 7) ^ (r & 7);
        gload_lds16(Abase + (size_t)r * 2048 + k0 + cg * 8, dst + chunk * 1024);
        gload_lds16(Bbase + (size_t)r * 2048 + k0 + cg * 8, dst + 16384 + chunk * 1024);
      }
    }

    char* As = smem + (t & 1) * 32768;
    char* Bs = As + 16384;
    bf16x8 af[2][4], bf_[2][4];
    #pragma unroll
    for (int kki = 0; kki < 2; ++kki) {
      #pragma unroll
      for (int m = 0; m < 4; ++m) {
        const int row = wr * 64 + m * 16 + (lane & 15);
        const int cg  = ((kki << 2) + (lane >> 4)) ^ (row & 7);
        af[kki][m] = *(const bf16x8*)(As + row * 128 + cg * 16);
      }
      #pragma unroll
      for (int n = 0; n < 4; ++n) {
        const int row = wc * 64 + n * 16 + (lane & 15);
        const int cg  = ((kki << 2) + (lane >> 4)) ^ (row & 7);
        bf_[kki][n] = *(const bf16x8*)(Bs + row * 128 + cg * 16);
      }
    }
    #pragma unroll
    for (int kki = 0; kki < 2; ++kki)
      #pragma unroll
      for (int m = 0; m < 4; ++m)
        #pragma unroll
        for (int n = 0; n < 4; ++n)
          acc[m][n] = MFMA_BF16(af[kki][m], bf_[kki][n], acc[m][n]);

    __syncthreads();
  }

  if (mode == 1) {
    // ---- K tile with fused RoPE: acc -> LDS (f32, col-XOR-swizzled), then
    //      rotate pairs (i, i+64) with theta = ylocal * f_i, store bf16 once.
    float* ls = (float*)smem;                // 128x128 f32 = 64 KB exactly
    #pragma unroll
    for (int m = 0; m < 4; ++m)
      #pragma unroll
      for (int n = 0; n < 4; ++n)
        #pragma unroll
        for (int j = 0; j < 4; ++j) {
          const int row = wr * 64 + m * 16 + ((lane >> 4) << 2) + j;
          const int col = wc * 64 + n * 16 + (lane & 15);
          ls[row * 128 + (col ^ ((row & 7) << 2))] = acc[m][n][j];
        }
    if (tid < 32) {                          // block-uniform trig, once
      const float f = __expf(-(float)tid * (9.2103403720f / 31.0f));
      float sn, cs;
      sincosf((float)ylocal * f, &sn, &cs);
      trigT[tid] = make_float2(cs, sn);
    }
    __syncthreads();
    const int r     = tid >> 1;              // token row within tile
    const int halfc = tid & 1;               // 0: dims 0..63, 1: dims 64..127
    const int sw    = (r & 7) << 2;
    ushort_t* dstp = Kb + (size_t)(blockIdx.x * 128 + r) * 512
                        + ylocal * 128 + halfc * 64;
    union { ushort_t us[64]; bf16x8 v8[8]; } outv;
    #pragma unroll
    for (int k4 = 0; k4 < 16; ++k4) {
      const int c0 = k4 * 4;                 // local col within this half
      const float4 xa = *(const float4*)&ls[r * 128 + ((halfc * 64 + c0) ^ sw)];
      if (c0 < 32) {
        const float4 xb = *(const float4*)&ls[r * 128 + (((halfc ^ 1) * 64 + c0) ^ sw)];
        #pragma unroll
        for (int e = 0; e < 4; ++e) {
          const float2 tv = trigT[c0 + e];   // broadcast read (uniform addr)
          const float cs = tv.x, sn = tv.y;
          const float x1 = halfc ? ((const float*)&xb)[e] : ((const float*)&xa)[e];
          const float x2 = halfc ? ((const float*)&xa)[e] : ((const float*)&xb)[e];
          outv.us[c0 + e] = f2bf(halfc ? (-x1 * sn + x2 * cs)
                                       : ( x1 * cs + x2 * sn));
        }
      } else {
        #pragma unroll
        for (int e = 0; e < 4; ++e)
          outv.us[c0 + e] = f2bf(((const float*)&xa)[e]);
      }
    }
    #pragma unroll
    for (int k8 = 0; k8 < 8; ++k8)
      *(bf16x8*)(dstp + k8 * 8) = outv.v8[k8];
    return;
  }

  const int row0 = blockIdx.x * 128 + wr * 64;
  const int col0 = ylocal * 128 + wc * 64;
  #pragma unroll
  for (int m = 0; m < 4; ++m) {
    #pragma unroll
    for (int n = 0; n < 4; ++n) {
      #pragma unroll
      for (int j = 0; j < 4; ++j) {
        const int gm = row0 + m * 16 + ((lane >> 4) << 2) + j;
        const int gn = col0 + n * 16 + (lane & 15);
        const float v = acc[m][n][j];
        if (mode == 0) {
          Qb[(size_t)gm * 2048 + gn] = f2bf(v);
        } else {
          const int bb = gm >> 11, t2 = gm & 2047;
          Vtb[(size_t)bb * 512 * 2048 + (size_t)gn * 2048 + t2] = f2bf(v);
        }
      }
    }
  }
}

// ---------------------------------------------------------------- GEMM  C = A * B^T
// (out-projection; T3 minimal 2-phase structure, BK=64)
template<int WMODE>
__global__ __launch_bounds__(256, 2)
void gemm_bt(const ushort_t* __restrict__ A, const ushort_t* __restrict__ B,
             void* __restrict__ Cout, int M, int N, int K) {
  __shared__ bf16x8 smem_v[4096];            // 64 KB
  char* smem = (char*)smem_v;
  const int tid  = threadIdx.x;
  const int lane = tid & 63;
  const int wave = tid >> 6;
  const int wr = wave >> 1, wc = wave & 1;
  const ushort_t* Abase = A + (size_t)blockIdx.x * 128 * K;
  const ushort_t* Bbase = B + (size_t)blockIdx.y * 128 * K;

  f32x4 acc[4][4] = {};
  const int nk = K >> 6;

  #pragma unroll
  for (int it = 0; it < 4; ++it) {
    const int chunk = it * 4 + wave;
    const int r  = chunk * 8 + (lane >> 3);
    const int cg = (lane & 7) ^ (r & 7);
    gload_lds16(Abase + (size_t)r * K + cg * 8, smem + chunk * 1024);
    gload_lds16(Bbase + (size_t)r * K + cg * 8, smem + 16384 + chunk * 1024);
  }
  __syncthreads();

  for (int t = 0; t < nk; ++t) {
    if (t + 1 < nk) {
      char* dst = smem + ((t + 1) & 1) * 32768;
      const int k0 = (t + 1) * 64;
      #pragma unroll
      for (int it = 0; it < 4; ++it) {
        const int chunk = it * 4 + wave;
        const int r  = chunk * 8 + (lane >> 3);
        const int cg = (lane & 7) ^ (r & 7);
        gload_lds16(Abase + (size_t)r * K + k0 + cg * 8, dst + chunk * 1024);
        gload_lds16(Bbase + (size_t)r * K + k0 + cg * 8, dst + 16384 + chunk * 1024);
      }
    }

    char* As = smem + (t & 1) * 32768;
    char* Bs = As + 16384;
    bf16x8 af[2][4], bf_[2][4];
    #pragma unroll
    for (int kki = 0; kki < 2; ++kki) {
      #pragma unroll
      for (int m = 0; m < 4; ++m) {
        const int row = wr * 64 + m * 16 + (lane & 15);
        const int cg  = ((kki << 2) + (lane >> 4)) ^ (row & 7);
        af[kki][m] = *(const bf16x8*)(As + row * 128 + cg * 16);
      }
      #pragma unroll
      for (int n = 0; n < 4; ++n) {
        const int row = wc * 64 + n * 16 + (lane & 15);
        const int cg  = ((kki << 2) + (lane >> 4)) ^ (row & 7);
        bf_[kki][n] = *(const bf16x8*)(Bs + row * 128 + cg * 16);
      }
    }
    #pragma unroll
    for (int kki = 0; kki < 2; ++kki)
      #pragma unroll
      for (int m = 0; m < 4; ++m)
        #pragma unroll
        for (int n = 0; n < 4; ++n)
          acc[m][n] = MFMA_BF16(af[kki][m], bf_[kki][n], acc[m][n]);

    __syncthreads();
  }

  const int row0 = blockIdx.x * 128 + wr * 64;
  const int col0 = blockIdx.y * 128 + wc * 64;
  #pragma unroll
  for (int m = 0; m < 4; ++m) {
    #pragma unroll
    for (int n = 0; n < 4; ++n) {
      #pragma unroll
      for (int j = 0; j < 4; ++j) {
        const int gm = row0 + m * 16 + ((lane >> 4) << 2) + j;
        const int gn = col0 + n * 16 + (lane & 15);
        const float v = acc[m][n][j];
        if (WMODE == 0) {
          ((ushort_t*)Cout)[(size_t)gm * N + gn] = f2bf(v);
        } else if (WMODE == 1) {
          ((float*)Cout)[(size_t)gm * N + gn] = v;
        } else {
          const int bb = gm >> 11, t2 = gm & 2047;
          ((ushort_t*)Cout)[(size_t)bb * N * 2048 + (size_t)gn * 2048 + t2] = f2bf(v);
        }
      }
    }
  }
}

// ---------------------------------------------------------------- flash attention
// r14 verified body + T15 PV-shift (pure instruction reorder, SAME barriers):
// hold P(t-1) and V-frags(t-1) in registers; per tile issue QK^T(t) MFMAs,
// then PV(t-1) MFMAs (independent -> back-to-back in matrix pipe), then
// softmax(t) VALU (needs only QK^T results; oacc rescale lands after PV(t-1)
// accumulation -> scale bookkeeping exact). Final pending PV flushed after
// the loop. `active` is monotone per wave -> single havePrev bool gates.
__global__ __launch_bounds__(256, 2)
void attn_kernel(const ushort_t* __restrict__ Q, const ushort_t* __restrict__ K,
                 const ushort_t* __restrict__ Vt, ushort_t* __restrict__ AO) {
  __shared__ bf16x8 smem_v[4096];            // 64 KB: 2 x (16KB K + 16KB V^T)
  char* smem = (char*)smem_v;
  const int tid  = threadIdx.x;
  const int lane = tid & 63;
  const int wq   = tid >> 6;
  const int ql   = lane & 31;
  const int hi   = lane >> 5;

  // ---- T1 remap (bijective on 512 blocks; lin%8 = XCD under round-robin);
  //      pairs (lin, lin+256): same (b,h), qt j & 15-j (const 34 tiles/CU pair)
  const int lin = (int)blockIdx.x + 16 * (int)blockIdx.y + 256 * (int)blockIdx.z;
  const int xcd = lin & 7;
  const int s   = lin >> 3;                  // 0..63 within XCD
  const int b   = xcd >> 2;
  const int kh  = xcd & 3;
  const int h   = (kh << 2) + (s & 3);
  const int s4  = s >> 2;                    // 0..15
  const int qt  = (s4 < 8) ? s4 : (23 - s4);

  const int q0b = qt * 128;
  const int qmin_w = q0b + wq * 32;
  const int qmax_w = qmin_w + 31;
  const int qrow = qmin_w + ql;

  const ushort_t* Qp = Q  + (size_t)b * 2048 * 2048 + (size_t)h  * 128;
  const ushort_t* Kp = K  + (size_t)b * 2048 * 512  + (size_t)kh * 128;
  const ushort_t* Vp = Vt + (size_t)b * 512 * 2048  + (size_t)kh * 128 * 2048;

  const int ntiles = (qt + 1) * 2;

  // ---- hoisted per-lane stage offsets (elements / LDS bytes), loop-invariant
  int offK[4], offV[4], ldK[4], ldV[4];
  #pragma unroll
  for (int it = 0; it < 4; ++it) {
    const int ck = it * 4 + wq;
    const int rK = ck * 4 + (lane >> 4);
    const int gK = (lane & 15) ^ (rK & 7);
    offK[it] = rK * 512 + gK * 8;  ldK[it] = ck * 1024;
    const int rV = ck * 8 + (lane >> 3);
    const int gV = (lane & 7) ^ (rV & 7);
    offV[it] = rV * 2048 + gV * 8; ldV[it] = 16384 + ck * 1024;
  }

  // ---- stage tile 0 into buffer 0 (hides under Q-load + RoPE)
  #pragma unroll
  for (int it = 0; it < 4; ++it) {
    gload_lds16(Kp + offK[it], smem + ldK[it]);
    gload_lds16(Vp + offV[it], smem + ldV[it]);
  }

  // ---- load Q fragments + fused head-indexed RoPE, with scale*log2e folded
  const float SCL = 0.08838834764831845f * 1.4426950408889634f;
  bf16x8 qf[8];
  #pragma unroll
  for (int ks = 0; ks < 8; ++ks)
    qf[ks] = *(const bf16x8*)(Qp + (size_t)qrow * 2048 + ks * 16 + hi * 8);
  #pragma unroll
  for (int ks = 0; ks < 2; ++ks) {           // rotated pairs: cols [0,32)+[64,96)
    union { bf16x8 v; ushort_t us[8]; } X1, X2;
    X1.v = qf[ks]; X2.v = qf[ks + 4];
    #pragma unroll
    for (int e = 0; e < 8; ++e) {
      const int i = ks * 16 + hi * 8 + e;
      const float f = __expf(-(float)i * (9.2103403720f / 31.0f));  // 10000^(-i/31)
      float sn, cs;
      sincosf((float)h * f, &sn, &cs);
      const float x1 = bf2f(X1.us[e]), x2 = bf2f(X2.us[e]);
      X1.us[e] = f2bf((x1 * cs + x2 * sn) * SCL);
      X2.us[e] = f2bf((-x1 * sn + x2 * cs) * SCL);
    }
    qf[ks] = X1.v; qf[ks + 4] = X2.v;
  }
  #pragma unroll
  for (int ks = 2; ks < 4; ++ks) {           // unrotated: cols [32,64)+[96,128)
    union { bf16x8 v; ushort_t us[8]; } X1, X2;
    X1.v = qf[ks]; X2.v = qf[ks + 4];
    #pragma unroll
    for (int e = 0; e < 8; ++e) {
      X1.us[e] = f2bf(bf2f(X1.us[e]) * SCL);
      X2.us[e] = f2bf(bf2f(X2.us[e]) * SCL);
    }
    qf[ks] = X1.v; qf[ks + 4] = X2.v;
  }

  float m_ = -3.0e38f, l_ = 0.f;
  f32x16 oacc[4] = {};
  bf16x8 vfr[4][4];                          // V-frags of the PENDING tile
  bf16x8 pa[4];                              // P-frags of the PENDING tile
  bool havePrev = false;

  __syncthreads();                           // tile 0 landed (full drain)

  for (int ti = 0; ti < ntiles; ++ti) {
    const int kv0 = ti * 64;
    if (ti + 1 < ntiles) {                   // issue next-tile stage first
      const ushort_t* Kt = Kp + (size_t)(kv0 + 64) * 512;   // uniform advance
      const ushort_t* Vn = Vp + (kv0 + 64);
      char* dst = smem + ((ti + 1) & 1) * 32768;
      #pragma unroll
      for (int it = 0; it < 4; ++it) {
        gload_lds16(Kt + offK[it], dst + ldK[it]);
        gload_lds16(Vn + offV[it], dst + ldV[it]);
      }
    }

    char* Ks = smem + (ti & 1) * 32768;
    char* Vs = Ks + 16384;
    const bool active = (kv0 <= qmax_w);     // wave-uniform, monotone

    f32x16 sacc[2] = {};
    if (active) {
      // ---- QK^T (swapped): lane holds S^T[key][q=ql], pre-scaled (log2)
      __builtin_amdgcn_s_setprio(1);
      #pragma unroll
      for (int kg = 0; kg < 2; ++kg) {
        const int key = kg * 32 + ql;
        #pragma unroll
        for (int ks = 0; ks < 8; ++ks) {
          const int g = ((ks << 1) + hi) ^ (key & 7);
          const bf16x8 kf = *(const bf16x8*)(Ks + key * 256 + g * 16);
          sacc[kg] = MFMA32_BF16(kf, qf[ks], sacc[kg]);
        }
      }
      __builtin_amdgcn_s_setprio(0);
    }

    // ---- PV of the PREVIOUS tile: independent of QK^T(t) -> overlaps its
    //      latency; accumulates into oacc BEFORE softmax(t)'s rescale.
    if (havePrev) {
      __builtin_amdgcn_s_setprio(1);
      #pragma unroll
      for (int dg = 0; dg < 4; ++dg)
        #pragma unroll
        for (int ks = 0; ks < 4; ++ks)
          oacc[dg] = MFMA32_BF16(pa[ks], vfr[dg][ks], oacc[dg]);
      __builtin_amdgcn_s_setprio(0);
    }

    if (active) {
      // ---- vf preload for THIS tile (consumed next iteration / epilogue)
      #pragma unroll
      for (int dg = 0; dg < 4; ++dg) {
        const int d = dg * 32 + ql;
        #pragma unroll
        for (int ks = 0; ks < 4; ++ks) {
          const int g = ((ks << 1) + hi) ^ (d & 7);
          vfr[dg][ks] = *(const bf16x8*)(Vs + d * 128 + g * 16);
        }
      }

      // ---- causal mask (diagonal tiles only)
      if (kv0 + 63 > qmin_w) {
        #pragma unroll
        for (int kg = 0; kg < 2; ++kg)
          #pragma unroll
          for (int r = 0; r < 16; ++r) {
            const int keyg = kv0 + kg * 32 + (r & 3) + 8 * (r >> 2) + 4 * hi;
            if (keyg > qrow) sacc[kg][r] = -3.0e38f;
          }
      }

      // ---- online softmax, log2 domain (T13 defer-max, THR ~ 8*log2e)
      float mx[8];
      #pragma unroll
      for (int i = 0; i < 8; ++i) {          // depth-3 tree over 32 values
        const int kg = i >> 2, base = (i & 3) * 4;
        mx[i] = fmaxf(fmaxf(sacc[kg][base], sacc[kg][base + 1]),
                      fmaxf(sacc[kg][base + 2], sacc[kg][base + 3]));
      }
      float pm = fmaxf(fmaxf(fmaxf(mx[0], mx[1]), fmaxf(mx[2], mx[3])),
                       fmaxf(fmaxf(mx[4], mx[5]), fmaxf(mx[6], mx[7])));
      pm = fmaxf(pm, __shfl_xor(pm, 32));

      if (__any(pm > m_ + 11.0f)) {
        const float mn = fmaxf(m_, pm);
        const float alpha = exp2_fast(m_ - mn);
        m_ = mn;
        l_ *= alpha;
        #pragma unroll
        for (int r = 0; r < 16; ++r) {
          const float ar = __shfl(alpha, (r & 3) + 8 * (r >> 2) + 4 * hi);
          #pragma unroll
          for (int dg = 0; dg < 4; ++dg) oacc[dg][r] *= ar;
        }
      }

      float rs0 = 0.f, rs1 = 0.f, rs2 = 0.f, rs3 = 0.f;  // 4 parallel chains
      #pragma unroll
      for (int kg = 0; kg < 2; ++kg)
        #pragma unroll
        for (int r = 0; r < 16; r += 4) {
          const float p0 = exp2_fast(sacc[kg][r]     - m_);
          const float p1 = exp2_fast(sacc[kg][r + 1] - m_);
          const float p2 = exp2_fast(sacc[kg][r + 2] - m_);
          const float p3 = exp2_fast(sacc[kg][r + 3] - m_);
          sacc[kg][r] = p0; sacc[kg][r + 1] = p1;
          sacc[kg][r + 2] = p2; sacc[kg][r + 3] = p3;
          rs0 += p0; rs1 += p1; rs2 += p2; rs3 += p3;
        }
      float rs = (rs0 + rs1) + (rs2 + rs3);
      rs += __shfl_xor(rs, 32);
      l_ += rs;

      // ---- P -> A-fragments via v_cvt_pk_bf16_f32 + permlane32_swap (T12)
      #pragma unroll
      for (int ks = 0; ks < 4; ++ks) {
        const int kg = ks >> 1;
        const int base = 8 * (ks & 1);
        union { uint32_t w[4]; bf16x8 v; } U;
        #pragma unroll
        for (int j = 0; j < 2; ++j) {
          uint32_t a  = cvtpk_bf16(sacc[kg][base + 2 * j],     sacc[kg][base + 2 * j + 1]);
          uint32_t bb = cvtpk_bf16(sacc[kg][base + 4 + 2 * j], sacc[kg][base + 4 + 2 * j + 1]);
          asm volatile("v_permlane32_swap_b32 %0, %1" : "+v"(a), "+v"(bb));
          U.w[j] = a; U.w[2 + j] = bb;
        }
        pa[ks] = U.v;
      }
    }
    havePrev = active;

    __syncthreads();   // drains: stage(ti+1) landed; all waves done with buf
  }

  // ---- flush the final pending PV
  if (havePrev) {
    #pragma unroll
    for (int dg = 0; dg < 4; ++dg)
      #pragma unroll
      for (int ks = 0; ks < 4; ++ks)
        oacc[dg] = MFMA32_BF16(pa[ks], vfr[dg][ks], oacc[dg]);
  }

  // ---- epilogue: normalize, store bf16
  const float linv = 1.0f / l_;
  ushort_t* AOp = AO + (size_t)b * 2048 * 2048 + (size_t)h * 128;
  #pragma unroll
  for (int r = 0; r < 16; ++r) {
    const int cr = (r & 3) + 8 * (r >> 2) + 4 * hi;
    const float li = __shfl(linv, cr);
    const int row = q0b + wq * 32 + cr;
    #pragma unroll
    for (int dg = 0; dg < 4; ++dg)
      AOp[(size_t)row * 2048 + dg * 32 + ql] = f2bf(oacc[dg][r] * li);
  }
}

// ---------------------------------------------------------------- launch
extern "C" void kernel_launch(void* const* d_in, const int* in_sizes, int n_in,
                              void* d_out, int out_size, void* d_ws, size_t ws_size,
                              hipStream_t stream) {
  const float* x  = (const float*)d_in[0];
  const float* wq = (const float*)d_in[1];
  const float* wk = (const float*)d_in[2];
  const float* wv = (const float*)d_in[3];
  const float* wo = (const float*)d_in[4];
  float* out = (float*)d_out;
  char* ws = (char*)d_ws;

  ushort_t* xb  = (ushort_t*)(ws);               // x   bf16  4096x2048
  ushort_t* wqb = (ushort_t*)(ws + 16777216);    // wq  bf16  2048x2048
  ushort_t* wkb = (ushort_t*)(ws + 25165824);    // wk  bf16   512x2048
  ushort_t* wvb = (ushort_t*)(ws + 27262976);    // wv  bf16   512x2048
  ushort_t* wob = (ushort_t*)(ws + 29360128);    // wo  bf16  2048x2048
  ushort_t* Qb  = (ushort_t*)(ws + 37748736);    // Q   bf16  4096x2048 (pre-RoPE)
  ushort_t* Kb  = (ushort_t*)(ws + 54525952);    // K   bf16  4096x512  (RoPE'd in GEMM)
  ushort_t* Vtb = (ushort_t*)(ws + 58720256);    // V^T bf16  [2][512][2048]
  ushort_t* AOb = (ushort_t*)(ws + 62914560);    // attn out bf16 4096x2048

  cvt_kernel<<<dim3(8192, 5), 256, 0, stream>>>(x, wq, wk, wv, wo,
                                                xb, wqb, wkb, wvb, wob);
  gemm_qkv<<<dim3(32, 24), 256, 0, stream>>>(xb, wqb, wkb, wvb, Qb, Kb, Vtb);
  attn_kernel<<<dim3(16, 16, 2), 256, 0, stream>>>(Qb, Kb, Vtb, AOb);
  gemm_bt<1><<<dim3(32, 16), 256, 0, stream>>>(AOb, wob, out, 4096, 2048, 2048);
}

// Round 16
// 190.109 us; speedup vs baseline: 1.0756x; 1.0756x over previous
//
#include <hip/hip_runtime.h>
#include <cstdint>
#include <cstddef>

typedef __attribute__((ext_vector_type(8))) short bf16x8;
typedef __attribute__((ext_vector_type(4))) float f32x4;
typedef __attribute__((ext_vector_type(16))) float f32x16;
typedef unsigned short ushort_t;

#define MFMA_BF16(a, b, c) __builtin_amdgcn_mfma_f32_16x16x32_bf16((a), (b), (c), 0, 0, 0)
#define MFMA32_BF16(a, b, c) __builtin_amdgcn_mfma_f32_32x32x16_bf16((a), (b), (c), 0, 0, 0)

__device__ __forceinline__ unsigned short f2bf(float f) {
  unsigned int u = __float_as_uint(f);
  u += 0x7fffu + ((u >> 16) & 1u);           // round-to-nearest-even
  return (unsigned short)(u >> 16);
}
__device__ __forceinline__ float bf2f(unsigned short h) {
  return __uint_as_float(((unsigned int)h) << 16);
}
// single-instruction 2^x (v_exp_f32 IS 2^x on CDNA)
__device__ __forceinline__ float exp2_fast(float x) {
  float r;
  asm("v_exp_f32 %0, %1" : "=v"(r) : "v"(x));
  return r;
}
// T12: packed f32x2 -> bf16x2 (lo = src0, hi = src1); no builtin on gfx950
__device__ __forceinline__ uint32_t cvtpk_bf16(float lo, float hi) {
  uint32_t r;
  asm("v_cvt_pk_bf16_f32 %0, %1, %2" : "=v"(r) : "v"(lo), "v"(hi));
  return r;
}

__device__ __forceinline__ void gload_lds16(const void* g, void* lds) {
  __builtin_amdgcn_global_load_lds(
      (const __attribute__((address_space(1))) void*)g,
      (__attribute__((address_space(3))) void*)lds, 16, 0, 0);
}

// ---------------------------------------------------------------- convert
__global__ __launch_bounds__(256)
void cvt_kernel(const float* __restrict__ x, const float* __restrict__ wq,
                const float* __restrict__ wk, const float* __restrict__ wv,
                const float* __restrict__ wo,
                ushort_t* __restrict__ xb, ushort_t* __restrict__ wqb,
                ushort_t* __restrict__ wkb, ushort_t* __restrict__ wvb,
                ushort_t* __restrict__ wob) {
  const float* src; ushort_t* dst; int n;
  switch (blockIdx.y) {
    case 0:  src = x;  dst = xb;  n = 8388608; break;
    case 1:  src = wq; dst = wqb; n = 4194304; break;
    case 2:  src = wk; dst = wkb; n = 1048576; break;
    case 3:  src = wv; dst = wvb; n = 1048576; break;
    default: src = wo; dst = wob; n = 4194304; break;
  }
  const int i = (int)(blockIdx.x * 256u + threadIdx.x) * 4;
  if (i >= n) return;
  const float4 v = *(const float4*)(src + i);
  union { unsigned short us[4]; unsigned long long u64; } pk;
  pk.us[0] = f2bf(v.x); pk.us[1] = f2bf(v.y);
  pk.us[2] = f2bf(v.z); pk.us[3] = f2bf(v.w);
  *(unsigned long long*)(dst + i) = pk.u64;
}

// ---------------------------------------------------------------- fused QKV GEMM
// BK=64, T3 minimal 2-phase drain0. blockIdx.y: 0..15 Q, 16..19 K, 20..23 V^T.
// K-mode epilogue: head-indexed RoPE fused (verified r14). LDS kept EXACTLY
// 65536 B — r15 showed +512B static LDS (trigT) pushed LDS_Block_Size to 66048
// and cost 24% on the whole kernel. Trig dedup now via ZERO-LDS wave
// broadcast: lane computes (cos,sin) for i = lane&31 once (1 sincosf, not 32);
// epilogue gathers with __shfl(., c0+e) — unrolled constant index lowers to
// v_readlane + SGPR broadcast.
__global__ __launch_bounds__(256, 2)
void gemm_qkv(const ushort_t* __restrict__ A,
              const ushort_t* __restrict__ WQ, const ushort_t* __restrict__ WK,
              const ushort_t* __restrict__ WV,
              ushort_t* __restrict__ Qb, ushort_t* __restrict__ Kb,
              ushort_t* __restrict__ Vtb) {
  __shared__ bf16x8 smem_v[4096];            // 64 KB exactly
  char* smem = (char*)smem_v;
  const int tid  = threadIdx.x;
  const int lane = tid & 63;
  const int wave = tid >> 6;
  const int wr = wave >> 1, wc = wave & 1;
  const int y = blockIdx.y;
  int mode, ylocal;
  const ushort_t* Bsel;
  if (y < 16)      { mode = 0; ylocal = y;      Bsel = WQ; }
  else if (y < 20) { mode = 1; ylocal = y - 16; Bsel = WK; }
  else             { mode = 2; ylocal = y - 20; Bsel = WV; }
  const ushort_t* Abase = A + (size_t)blockIdx.x * 128 * 2048;
  const ushort_t* Bbase = Bsel + (size_t)ylocal * 128 * 2048;

  f32x4 acc[4][4] = {};

  #pragma unroll
  for (int it = 0; it < 4; ++it) {
    const int chunk = it * 4 + wave;
    const int r  = chunk * 8 + (lane >> 3);
    const int cg = (lane & 7) ^ (r & 7);
    gload_lds16(Abase + (size_t)r * 2048 + cg * 8, smem + chunk * 1024);
    gload_lds16(Bbase + (size_t)r * 2048 + cg * 8, smem + 16384 + chunk * 1024);
  }
  __syncthreads();

  for (int t = 0; t < 32; ++t) {
    if (t + 1 < 32) {                        // issue next stage first
      char* dst = smem + ((t + 1) & 1) * 32768;
      const int k0 = (t + 1) * 64;
      #pragma unroll
      for (int it = 0; it < 4; ++it) {
        const int chunk = it * 4 + wave;
        const int r  = chunk * 8 + (lane >> 3);
        const int cg = (lane & 7) ^ (r & 7);
        gload_lds16(Abase + (size_t)r * 2048 + k0 + cg * 8, dst + chunk * 1024);
        gload_lds16(Bbase + (size_t)r * 2048 + k0 + cg * 8, dst + 16384 + chunk * 1024);
      }
    }

    char* As = smem + (t & 1) * 32768;
    char* Bs = As + 16384;
    bf16x8 af[2][4], bf_[2][4];
    #pragma unroll
    for (int kki = 0; kki < 2; ++kki) {
      #pragma unroll
      for (int m = 0; m < 4; ++m) {
        const int row = wr * 64 + m * 16 + (lane & 15);
        const int cg  = ((kki << 2) + (lane >> 4)) ^ (row & 7);
        af[kki][m] = *(const bf16x8*)(As + row * 128 + cg * 16);
      }
      #pragma unroll
      for (int n = 0; n < 4; ++n) {
        const int row = wc * 64 + n * 16 + (lane & 15);
        const int cg  = ((kki << 2) + (lane >> 4)) ^ (row & 7);
        bf_[kki][n] = *(const bf16x8*)(Bs + row * 128 + cg * 16);
      }
    }
    #pragma unroll
    for (int kki = 0; kki < 2; ++kki)
      #pragma unroll
      for (int m = 0; m < 4; ++m)
        #pragma unroll
        for (int n = 0; n < 4; ++n)
          acc[m][n] = MFMA_BF16(af[kki][m], bf_[kki][n], acc[m][n]);

    __syncthreads();
  }

  if (mode == 1) {
    // ---- K tile with fused RoPE: acc -> LDS (f32, col-XOR-swizzled), then
    //      rotate pairs (i, i+64) with theta = ylocal * f_i, store bf16 once.
    float* ls = (float*)smem;                // 128x128 f32 = 64 KB exactly
    #pragma unroll
    for (int m = 0; m < 4; ++m)
      #pragma unroll
      for (int n = 0; n < 4; ++n)
        #pragma unroll
        for (int j = 0; j < 4; ++j) {
          const int row = wr * 64 + m * 16 + ((lane >> 4) << 2) + j;
          const int col = wc * 64 + n * 16 + (lane & 15);
          ls[row * 128 + (col ^ ((row & 7) << 2))] = acc[m][n][j];
        }
    // per-lane trig for i = lane&31 (block-uniform theta set; 1 sincosf)
    const float fme = __expf(-(float)(lane & 31) * (9.2103403720f / 31.0f));
    float snm, csm;
    sincosf((float)ylocal * fme, &snm, &csm);
    __syncthreads();
    const int r     = tid >> 1;              // token row within tile
    const int halfc = tid & 1;               // 0: dims 0..63, 1: dims 64..127
    const int sw    = (r & 7) << 2;
    ushort_t* dstp = Kb + (size_t)(blockIdx.x * 128 + r) * 512
                        + ylocal * 128 + halfc * 64;
    union { ushort_t us[64]; bf16x8 v8[8]; } outv;
    #pragma unroll
    for (int k4 = 0; k4 < 16; ++k4) {
      const int c0 = k4 * 4;                 // local col within this half
      const float4 xa = *(const float4*)&ls[r * 128 + ((halfc * 64 + c0) ^ sw)];
      if (c0 < 32) {
        const float4 xb = *(const float4*)&ls[r * 128 + (((halfc ^ 1) * 64 + c0) ^ sw)];
        #pragma unroll
        for (int e = 0; e < 4; ++e) {
          const float cs = __shfl(csm, c0 + e);   // const idx -> readlane bcast
          const float sn = __shfl(snm, c0 + e);
          const float x1 = halfc ? ((const float*)&xb)[e] : ((const float*)&xa)[e];
          const float x2 = halfc ? ((const float*)&xa)[e] : ((const float*)&xb)[e];
          outv.us[c0 + e] = f2bf(halfc ? (-x1 * sn + x2 * cs)
                                       : ( x1 * cs + x2 * sn));
        }
      } else {
        #pragma unroll
        for (int e = 0; e < 4; ++e)
          outv.us[c0 + e] = f2bf(((const float*)&xa)[e]);
      }
    }
    #pragma unroll
    for (int k8 = 0; k8 < 8; ++k8)
      *(bf16x8*)(dstp + k8 * 8) = outv.v8[k8];
    return;
  }

  const int row0 = blockIdx.x * 128 + wr * 64;
  const int col0 = ylocal * 128 + wc * 64;
  #pragma unroll
  for (int m = 0; m < 4; ++m) {
    #pragma unroll
    for (int n = 0; n < 4; ++n) {
      #pragma unroll
      for (int j = 0; j < 4; ++j) {
        const int gm = row0 + m * 16 + ((lane >> 4) << 2) + j;
        const int gn = col0 + n * 16 + (lane & 15);
        const float v = acc[m][n][j];
        if (mode == 0) {
          Qb[(size_t)gm * 2048 + gn] = f2bf(v);
        } else {
          const int bb = gm >> 11, t2 = gm & 2047;
          Vtb[(size_t)bb * 512 * 2048 + (size_t)gn * 2048 + t2] = f2bf(v);
        }
      }
    }
  }
}

// ---------------------------------------------------------------- GEMM  C = A * B^T
// (out-projection; T3 minimal 2-phase structure, BK=64)
template<int WMODE>
__global__ __launch_bounds__(256, 2)
void gemm_bt(const ushort_t* __restrict__ A, const ushort_t* __restrict__ B,
             void* __restrict__ Cout, int M, int N, int K) {
  __shared__ bf16x8 smem_v[4096];            // 64 KB
  char* smem = (char*)smem_v;
  const int tid  = threadIdx.x;
  const int lane = tid & 63;
  const int wave = tid >> 6;
  const int wr = wave >> 1, wc = wave & 1;
  const ushort_t* Abase = A + (size_t)blockIdx.x * 128 * K;
  const ushort_t* Bbase = B + (size_t)blockIdx.y * 128 * K;

  f32x4 acc[4][4] = {};
  const int nk = K >> 6;

  #pragma unroll
  for (int it = 0; it < 4; ++it) {
    const int chunk = it * 4 + wave;
    const int r  = chunk * 8 + (lane >> 3);
    const int cg = (lane & 7) ^ (r & 7);
    gload_lds16(Abase + (size_t)r * K + cg * 8, smem + chunk * 1024);
    gload_lds16(Bbase + (size_t)r * K + cg * 8, smem + 16384 + chunk * 1024);
  }
  __syncthreads();

  for (int t = 0; t < nk; ++t) {
    if (t + 1 < nk) {
      char* dst = smem + ((t + 1) & 1) * 32768;
      const int k0 = (t + 1) * 64;
      #pragma unroll
      for (int it = 0; it < 4; ++it) {
        const int chunk = it * 4 + wave;
        const int r  = chunk * 8 + (lane >> 3);
        const int cg = (lane & 7) ^ (r & 7);
        gload_lds16(Abase + (size_t)r * K + k0 + cg * 8, dst + chunk * 1024);
        gload_lds16(Bbase + (size_t)r * K + k0 + cg * 8, dst + 16384 + chunk * 1024);
      }
    }

    char* As = smem + (t & 1) * 32768;
    char* Bs = As + 16384;
    bf16x8 af[2][4], bf_[2][4];
    #pragma unroll
    for (int kki = 0; kki < 2; ++kki) {
      #pragma unroll
      for (int m = 0; m < 4; ++m) {
        const int row = wr * 64 + m * 16 + (lane & 15);
        const int cg  = ((kki << 2) + (lane >> 4)) ^ (row & 7);
        af[kki][m] = *(const bf16x8*)(As + row * 128 + cg * 16);
      }
      #pragma unroll
      for (int n = 0; n < 4; ++n) {
        const int row = wc * 64 + n * 16 + (lane & 15);
        const int cg  = ((kki << 2) + (lane >> 4)) ^ (row & 7);
        bf_[kki][n] = *(const bf16x8*)(Bs + row * 128 + cg * 16);
      }
    }
    #pragma unroll
    for (int kki = 0; kki < 2; ++kki)
      #pragma unroll
      for (int m = 0; m < 4; ++m)
        #pragma unroll
        for (int n = 0; n < 4; ++n)
          acc[m][n] = MFMA_BF16(af[kki][m], bf_[kki][n], acc[m][n]);

    __syncthreads();
  }

  const int row0 = blockIdx.x * 128 + wr * 64;
  const int col0 = blockIdx.y * 128 + wc * 64;
  #pragma unroll
  for (int m = 0; m < 4; ++m) {
    #pragma unroll
    for (int n = 0; n < 4; ++n) {
      #pragma unroll
      for (int j = 0; j < 4; ++j) {
        const int gm = row0 + m * 16 + ((lane >> 4) << 2) + j;
        const int gn = col0 + n * 16 + (lane & 15);
        const float v = acc[m][n][j];
        if (WMODE == 0) {
          ((ushort_t*)Cout)[(size_t)gm * N + gn] = f2bf(v);
        } else if (WMODE == 1) {
          ((float*)Cout)[(size_t)gm * N + gn] = v;
        } else {
          const int bb = gm >> 11, t2 = gm & 2047;
          ((ushort_t*)Cout)[(size_t)bb * N * 2048 + (size_t)gn * 2048 + t2] = f2bf(v);
        }
      }
    }
  }
}

// ---------------------------------------------------------------- flash attention
// r15 verified body (passed; T15 PV-shift neutral, kept): 4 waves x 32 q-rows,
// KVBLK=64, swapped QK^T, exp2-domain softmax (__shfl_xor reductions), T12
// cvt_pk+permlane P-pack, T13 defer-max, fused Q-RoPE, vf preload, hoisted
// stage offsets, T1 XCD remap, T3 drain0 sync.
__global__ __launch_bounds__(256, 2)
void attn_kernel(const ushort_t* __restrict__ Q, const ushort_t* __restrict__ K,
                 const ushort_t* __restrict__ Vt, ushort_t* __restrict__ AO) {
  __shared__ bf16x8 smem_v[4096];            // 64 KB: 2 x (16KB K + 16KB V^T)
  char* smem = (char*)smem_v;
  const int tid  = threadIdx.x;
  const int lane = tid & 63;
  const int wq   = tid >> 6;
  const int ql   = lane & 31;
  const int hi   = lane >> 5;

  // ---- T1 remap (bijective on 512 blocks; lin%8 = XCD under round-robin);
  //      pairs (lin, lin+256): same (b,h), qt j & 15-j (const 34 tiles/CU pair)
  const int lin = (int)blockIdx.x + 16 * (int)blockIdx.y + 256 * (int)blockIdx.z;
  const int xcd = lin & 7;
  const int s   = lin >> 3;                  // 0..63 within XCD
  const int b   = xcd >> 2;
  const int kh  = xcd & 3;
  const int h   = (kh << 2) + (s & 3);
  const int s4  = s >> 2;                    // 0..15
  const int qt  = (s4 < 8) ? s4 : (23 - s4);

  const int q0b = qt * 128;
  const int qmin_w = q0b + wq * 32;
  const int qmax_w = qmin_w + 31;
  const int qrow = qmin_w + ql;

  const ushort_t* Qp = Q  + (size_t)b * 2048 * 2048 + (size_t)h  * 128;
  const ushort_t* Kp = K  + (size_t)b * 2048 * 512  + (size_t)kh * 128;
  const ushort_t* Vp = Vt + (size_t)b * 512 * 2048  + (size_t)kh * 128 * 2048;

  const int ntiles = (qt + 1) * 2;

  // ---- hoisted per-lane stage offsets (elements / LDS bytes), loop-invariant
  int offK[4], offV[4], ldK[4], ldV[4];
  #pragma unroll
  for (int it = 0; it < 4; ++it) {
    const int ck = it * 4 + wq;
    const int rK = ck * 4 + (lane >> 4);
    const int gK = (lane & 15) ^ (rK & 7);
    offK[it] = rK * 512 + gK * 8;  ldK[it] = ck * 1024;
    const int rV = ck * 8 + (lane >> 3);
    const int gV = (lane & 7) ^ (rV & 7);
    offV[it] = rV * 2048 + gV * 8; ldV[it] = 16384 + ck * 1024;
  }

  // ---- stage tile 0 into buffer 0 (hides under Q-load + RoPE)
  #pragma unroll
  for (int it = 0; it < 4; ++it) {
    gload_lds16(Kp + offK[it], smem + ldK[it]);
    gload_lds16(Vp + offV[it], smem + ldV[it]);
  }

  // ---- load Q fragments + fused head-indexed RoPE, with scale*log2e folded
  const float SCL = 0.08838834764831845f * 1.4426950408889634f;
  bf16x8 qf[8];
  #pragma unroll
  for (int ks = 0; ks < 8; ++ks)
    qf[ks] = *(const bf16x8*)(Qp + (size_t)qrow * 2048 + ks * 16 + hi * 8);
  #pragma unroll
  for (int ks = 0; ks < 2; ++ks) {           // rotated pairs: cols [0,32)+[64,96)
    union { bf16x8 v; ushort_t us[8]; } X1, X2;
    X1.v = qf[ks]; X2.v = qf[ks + 4];
    #pragma unroll
    for (int e = 0; e < 8; ++e) {
      const int i = ks * 16 + hi * 8 + e;
      const float f = __expf(-(float)i * (9.2103403720f / 31.0f));  // 10000^(-i/31)
      float sn, cs;
      sincosf((float)h * f, &sn, &cs);
      const float x1 = bf2f(X1.us[e]), x2 = bf2f(X2.us[e]);
      X1.us[e] = f2bf((x1 * cs + x2 * sn) * SCL);
      X2.us[e] = f2bf((-x1 * sn + x2 * cs) * SCL);
    }
    qf[ks] = X1.v; qf[ks + 4] = X2.v;
  }
  #pragma unroll
  for (int ks = 2; ks < 4; ++ks) {           // unrotated: cols [32,64)+[96,128)
    union { bf16x8 v; ushort_t us[8]; } X1, X2;
    X1.v = qf[ks]; X2.v = qf[ks + 4];
    #pragma unroll
    for (int e = 0; e < 8; ++e) {
      X1.us[e] = f2bf(bf2f(X1.us[e]) * SCL);
      X2.us[e] = f2bf(bf2f(X2.us[e]) * SCL);
    }
    qf[ks] = X1.v; qf[ks + 4] = X2.v;
  }

  float m_ = -3.0e38f, l_ = 0.f;
  f32x16 oacc[4] = {};
  bf16x8 vfr[4][4];                          // V-frags of the PENDING tile
  bf16x8 pa[4];                              // P-frags of the PENDING tile
  bool havePrev = false;

  __syncthreads();                           // tile 0 landed (full drain)

  for (int ti = 0; ti < ntiles; ++ti) {
    const int kv0 = ti * 64;
    if (ti + 1 < ntiles) {                   // issue next-tile stage first
      const ushort_t* Kt = Kp + (size_t)(kv0 + 64) * 512;   // uniform advance
      const ushort_t* Vn = Vp + (kv0 + 64);
      char* dst = smem + ((ti + 1) & 1) * 32768;
      #pragma unroll
      for (int it = 0; it < 4; ++it) {
        gload_lds16(Kt + offK[it], dst + ldK[it]);
        gload_lds16(Vn + offV[it], dst + ldV[it]);
      }
    }

    char* Ks = smem + (ti & 1) * 32768;
    char* Vs = Ks + 16384;
    const bool active = (kv0 <= qmax_w);     // wave-uniform, monotone

    f32x16 sacc[2] = {};
    if (active) {
      // ---- QK^T (swapped): lane holds S^T[key][q=ql], pre-scaled (log2)
      __builtin_amdgcn_s_setprio(1);
      #pragma unroll
      for (int kg = 0; kg < 2; ++kg) {
        const int key = kg * 32 + ql;
        #pragma unroll
        for (int ks = 0; ks < 8; ++ks) {
          const int g = ((ks << 1) + hi) ^ (key & 7);
          const bf16x8 kf = *(const bf16x8*)(Ks + key * 256 + g * 16);
          sacc[kg] = MFMA32_BF16(kf, qf[ks], sacc[kg]);
        }
      }
      __builtin_amdgcn_s_setprio(0);
    }

    // ---- PV of the PREVIOUS tile: independent of QK^T(t) -> overlaps its
    //      latency; accumulates into oacc BEFORE softmax(t)'s rescale.
    if (havePrev) {
      __builtin_amdgcn_s_setprio(1);
      #pragma unroll
      for (int dg = 0; dg < 4; ++dg)
        #pragma unroll
        for (int ks = 0; ks < 4; ++ks)
          oacc[dg] = MFMA32_BF16(pa[ks], vfr[dg][ks], oacc[dg]);
      __builtin_amdgcn_s_setprio(0);
    }

    if (active) {
      // ---- vf preload for THIS tile (consumed next iteration / epilogue)
      #pragma unroll
      for (int dg = 0; dg < 4; ++dg) {
        const int d = dg * 32 + ql;
        #pragma unroll
        for (int ks = 0; ks < 4; ++ks) {
          const int g = ((ks << 1) + hi) ^ (d & 7);
          vfr[dg][ks] = *(const bf16x8*)(Vs + d * 128 + g * 16);
        }
      }

      // ---- causal mask (diagonal tiles only)
      if (kv0 + 63 > qmin_w) {
        #pragma unroll
        for (int kg = 0; kg < 2; ++kg)
          #pragma unroll
          for (int r = 0; r < 16; ++r) {
            const int keyg = kv0 + kg * 32 + (r & 3) + 8 * (r >> 2) + 4 * hi;
            if (keyg > qrow) sacc[kg][r] = -3.0e38f;
          }
      }

      // ---- online softmax, log2 domain (T13 defer-max, THR ~ 8*log2e)
      float mx[8];
      #pragma unroll
      for (int i = 0; i < 8; ++i) {          // depth-3 tree over 32 values
        const int kg = i >> 2, base = (i & 3) * 4;
        mx[i] = fmaxf(fmaxf(sacc[kg][base], sacc[kg][base + 1]),
                      fmaxf(sacc[kg][base + 2], sacc[kg][base + 3]));
      }
      float pm = fmaxf(fmaxf(fmaxf(mx[0], mx[1]), fmaxf(mx[2], mx[3])),
                       fmaxf(fmaxf(mx[4], mx[5]), fmaxf(mx[6], mx[7])));
      pm = fmaxf(pm, __shfl_xor(pm, 32));

      if (__any(pm > m_ + 11.0f)) {
        const float mn = fmaxf(m_, pm);
        const float alpha = exp2_fast(m_ - mn);
        m_ = mn;
        l_ *= alpha;
        #pragma unroll
        for (int r = 0; r < 16; ++r) {
          const float ar = __shfl(alpha, (r & 3) + 8 * (r >> 2) + 4 * hi);
          #pragma unroll
          for (int dg = 0; dg < 4; ++dg) oacc[dg][r] *= ar;
        }
      }

      float rs0 = 0.f, rs1 = 0.f, rs2 = 0.f, rs3 = 0.f;  // 4 parallel chains
      #pragma unroll
      for (int kg = 0; kg < 2; ++kg)
        #pragma unroll
        for (int r = 0; r < 16; r += 4) {
          const float p0 = exp2_fast(sacc[kg][r]     - m_);
          const float p1 = exp2_fast(sacc[kg][r + 1] - m_);
          const float p2 = exp2_fast(sacc[kg][r + 2] - m_);
          const float p3 = exp2_fast(sacc[kg][r + 3] - m_);
          sacc[kg][r] = p0; sacc[kg][r + 1] = p1;
          sacc[kg][r + 2] = p2; sacc[kg][r + 3] = p3;
          rs0 += p0; rs1 += p1; rs2 += p2; rs3 += p3;
        }
      float rs = (rs0 + rs1) + (rs2 + rs3);
      rs += __shfl_xor(rs, 32);
      l_ += rs;

      // ---- P -> A-fragments via v_cvt_pk_bf16_f32 + permlane32_swap (T12)
      #pragma unroll
      for (int ks = 0; ks < 4; ++ks) {
        const int kg = ks >> 1;
        const int base = 8 * (ks & 1);
        union { uint32_t w[4]; bf16x8 v; } U;
        #pragma unroll
        for (int j = 0; j < 2; ++j) {
          uint32_t a  = cvtpk_bf16(sacc[kg][base + 2 * j],     sacc[kg][base + 2 * j + 1]);
          uint32_t bb = cvtpk_bf16(sacc[kg][base + 4 + 2 * j], sacc[kg][base + 4 + 2 * j + 1]);
          asm volatile("v_permlane32_swap_b32 %0, %1" : "+v"(a), "+v"(bb));
          U.w[j] = a; U.w[2 + j] = bb;
        }
        pa[ks] = U.v;
      }
    }
    havePrev = active;

    __syncthreads();   // drains: stage(ti+1) landed; all waves done with buf
  }

  // ---- flush the final pending PV
  if (havePrev) {
    #pragma unroll
    for (int dg = 0; dg < 4; ++dg)
      #pragma unroll
      for (int ks = 0; ks < 4; ++ks)
        oacc[dg] = MFMA32_BF16(pa[ks], vfr[dg][ks], oacc[dg]);
  }

  // ---- epilogue: normalize, store bf16
  const float linv = 1.0f / l_;
  ushort_t* AOp = AO + (size_t)b * 2048 * 2048 + (size_t)h * 128;
  #pragma unroll
  for (int r = 0; r < 16; ++r) {
    const int cr = (r & 3) + 8 * (r >> 2) + 4 * hi;
    const float li = __shfl(linv, cr);
    const int row = q0b + wq * 32 + cr;
    #pragma unroll
    for (int dg = 0; dg < 4; ++dg)
      AOp[(size_t)row * 2048 + dg * 32 + ql] = f2bf(oacc[dg][r] * li);
  }
}

// ---------------------------------------------------------------- launch
extern "C" void kernel_launch(void* const* d_in, const int* in_sizes, int n_in,
                              void* d_out, int out_size, void* d_ws, size_t ws_size,
                              hipStream_t stream) {
  const float* x  = (const float*)d_in[0];
  const float* wq = (const float*)d_in[1];
  const float* wk = (const float*)d_in[2];
  const float* wv = (const float*)d_in[3];
  const float* wo = (const float*)d_in[4];
  float* out = (float*)d_out;
  char* ws = (char*)d_ws;

  ushort_t* xb  = (ushort_t*)(ws);               // x   bf16  4096x2048
  ushort_t* wqb = (ushort_t*)(ws + 16777216);    // wq  bf16  2048x2048
  ushort_t* wkb = (ushort_t*)(ws + 25165824);    // wk  bf16   512x2048
  ushort_t* wvb = (ushort_t*)(ws + 27262976);    // wv  bf16   512x2048
  ushort_t* wob = (ushort_t*)(ws + 29360128);    // wo  bf16  2048x2048
  ushort_t* Qb  = (ushort_t*)(ws + 37748736);    // Q   bf16  4096x2048 (pre-RoPE)
  ushort_t* Kb  = (ushort_t*)(ws + 54525952);    // K   bf16  4096x512  (RoPE'd in GEMM)
  ushort_t* Vtb = (ushort_t*)(ws + 58720256);    // V^T bf16  [2][512][2048]
  ushort_t* AOb = (ushort_t*)(ws + 62914560);    // attn out bf16 4096x2048

  cvt_kernel<<<dim3(8192, 5), 256, 0, stream>>>(x, wq, wk, wv, wo,
                                                xb, wqb, wkb, wvb, wob);
  gemm_qkv<<<dim3(32, 24), 256, 0, stream>>>(xb, wqb, wkb, wvb, Qb, Kb, Vtb);
  attn_kernel<<<dim3(16, 16, 2), 256, 0, stream>>>(Qb, Kb, Vtb, AOb);
  gemm_bt<1><<<dim3(32, 16), 256, 0, stream>>>(AOb, wob, out, 4096, 2048, 2048);
}

// Round 17
// 185.171 us; speedup vs baseline: 1.1043x; 1.0267x over previous
//
#include <hip/hip_runtime.h>
#include <cstdint>
#include <cstddef>

typedef __attribute__((ext_vector_type(8))) short bf16x8;
typedef __attribute__((ext_vector_type(4))) float f32x4;
typedef __attribute__((ext_vector_type(16))) float f32x16;
typedef unsigned short ushort_t;

#define MFMA_BF16(a, b, c) __builtin_amdgcn_mfma_f32_16x16x32_bf16((a), (b), (c), 0, 0, 0)
#define MFMA32_BF16(a, b, c) __builtin_amdgcn_mfma_f32_32x32x16_bf16((a), (b), (c), 0, 0, 0)

__device__ __forceinline__ unsigned short f2bf(float f) {
  unsigned int u = __float_as_uint(f);
  u += 0x7fffu + ((u >> 16) & 1u);           // round-to-nearest-even
  return (unsigned short)(u >> 16);
}
__device__ __forceinline__ float bf2f(unsigned short h) {
  return __uint_as_float(((unsigned int)h) << 16);
}
// single-instruction 2^x (v_exp_f32 IS 2^x on CDNA)
__device__ __forceinline__ float exp2_fast(float x) {
  float r;
  asm("v_exp_f32 %0, %1" : "=v"(r) : "v"(x));
  return r;
}
// T12: packed f32x2 -> bf16x2 (lo = src0, hi = src1); no builtin on gfx950
__device__ __forceinline__ uint32_t cvtpk_bf16(float lo, float hi) {
  uint32_t r;
  asm("v_cvt_pk_bf16_f32 %0, %1, %2" : "=v"(r) : "v"(lo), "v"(hi));
  return r;
}

__device__ __forceinline__ void gload_lds16(const void* g, void* lds) {
  __builtin_amdgcn_global_load_lds(
      (const __attribute__((address_space(1))) void*)g,
      (__attribute__((address_space(3))) void*)lds, 16, 0, 0);
}

// ---------------------------------------------------------------- convert
__global__ __launch_bounds__(256)
void cvt_kernel(const float* __restrict__ x, const float* __restrict__ wq,
                const float* __restrict__ wk, const float* __restrict__ wv,
                const float* __restrict__ wo,
                ushort_t* __restrict__ xb, ushort_t* __restrict__ wqb,
                ushort_t* __restrict__ wkb, ushort_t* __restrict__ wvb,
                ushort_t* __restrict__ wob) {
  const float* src; ushort_t* dst; int n;
  switch (blockIdx.y) {
    case 0:  src = x;  dst = xb;  n = 8388608; break;
    case 1:  src = wq; dst = wqb; n = 4194304; break;
    case 2:  src = wk; dst = wkb; n = 1048576; break;
    case 3:  src = wv; dst = wvb; n = 1048576; break;
    default: src = wo; dst = wob; n = 4194304; break;
  }
  const int i = (int)(blockIdx.x * 256u + threadIdx.x) * 4;
  if (i >= n) return;
  const float4 v = *(const float4*)(src + i);
  union { unsigned short us[4]; unsigned long long u64; } pk;
  pk.us[0] = f2bf(v.x); pk.us[1] = f2bf(v.y);
  pk.us[2] = f2bf(v.z); pk.us[3] = f2bf(v.w);
  *(unsigned long long*)(dst + i) = pk.u64;
}

// ---------------------------------------------------------------- fused QKV GEMM
// (r16-verified: BK=64, T3 drain0, K-RoPE epilogue with zero-LDS shfl trig,
//  LDS exactly 65536 B — the r15 +512B overflow cost 24%.)
__global__ __launch_bounds__(256, 2)
void gemm_qkv(const ushort_t* __restrict__ A,
              const ushort_t* __restrict__ WQ, const ushort_t* __restrict__ WK,
              const ushort_t* __restrict__ WV,
              ushort_t* __restrict__ Qb, ushort_t* __restrict__ Kb,
              ushort_t* __restrict__ Vtb) {
  __shared__ bf16x8 smem_v[4096];            // 64 KB exactly
  char* smem = (char*)smem_v;
  const int tid  = threadIdx.x;
  const int lane = tid & 63;
  const int wave = tid >> 6;
  const int wr = wave >> 1, wc = wave & 1;
  const int y = blockIdx.y;
  int mode, ylocal;
  const ushort_t* Bsel;
  if (y < 16)      { mode = 0; ylocal = y;      Bsel = WQ; }
  else if (y < 20) { mode = 1; ylocal = y - 16; Bsel = WK; }
  else             { mode = 2; ylocal = y - 20; Bsel = WV; }
  const ushort_t* Abase = A + (size_t)blockIdx.x * 128 * 2048;
  const ushort_t* Bbase = Bsel + (size_t)ylocal * 128 * 2048;

  f32x4 acc[4][4] = {};

  #pragma unroll
  for (int it = 0; it < 4; ++it) {
    const int chunk = it * 4 + wave;
    const int r  = chunk * 8 + (lane >> 3);
    const int cg = (lane & 7) ^ (r & 7);
    gload_lds16(Abase + (size_t)r * 2048 + cg * 8, smem + chunk * 1024);
    gload_lds16(Bbase + (size_t)r * 2048 + cg * 8, smem + 16384 + chunk * 1024);
  }
  __syncthreads();

  for (int t = 0; t < 32; ++t) {
    if (t + 1 < 32) {                        // issue next stage first
      char* dst = smem + ((t + 1) & 1) * 32768;
      const int k0 = (t + 1) * 64;
      #pragma unroll
      for (int it = 0; it < 4; ++it) {
        const int chunk = it * 4 + wave;
        const int r  = chunk * 8 + (lane >> 3);
        const int cg = (lane & 7) ^ (r & 7);
        gload_lds16(Abase + (size_t)r * 2048 + k0 + cg * 8, dst + chunk * 1024);
        gload_lds16(Bbase + (size_t)r * 2048 + k0 + cg * 8, dst + 16384 + chunk * 1024);
      }
    }

    char* As = smem + (t & 1) * 32768;
    char* Bs = As + 16384;
    bf16x8 af[2][4], bf_[2][4];
    #pragma unroll
    for (int kki = 0; kki < 2; ++kki) {
      #pragma unroll
      for (int m = 0; m < 4; ++m) {
        const int row = wr * 64 + m * 16 + (lane & 15);
        const int cg  = ((kki << 2) + (lane >> 4)) ^ (row & 7);
        af[kki][m] = *(const bf16x8*)(As + row * 128 + cg * 16);
      }
      #pragma unroll
      for (int n = 0; n < 4; ++n) {
        const int row = wc * 64 + n * 16 + (lane & 15);
        const int cg  = ((kki << 2) + (lane >> 4)) ^ (row & 7);
        bf_[kki][n] = *(const bf16x8*)(Bs + row * 128 + cg * 16);
      }
    }
    #pragma unroll
    for (int kki = 0; kki < 2; ++kki)
      #pragma unroll
      for (int m = 0; m < 4; ++m)
        #pragma unroll
        for (int n = 0; n < 4; ++n)
          acc[m][n] = MFMA_BF16(af[kki][m], bf_[kki][n], acc[m][n]);

    __syncthreads();
  }

  if (mode == 1) {
    // ---- K tile with fused RoPE: acc -> LDS (f32, col-XOR-swizzled), then
    //      rotate pairs (i, i+64) with theta = ylocal * f_i, store bf16 once.
    float* ls = (float*)smem;                // 128x128 f32 = 64 KB exactly
    #pragma unroll
    for (int m = 0; m < 4; ++m)
      #pragma unroll
      for (int n = 0; n < 4; ++n)
        #pragma unroll
        for (int j = 0; j < 4; ++j) {
          const int row = wr * 64 + m * 16 + ((lane >> 4) << 2) + j;
          const int col = wc * 64 + n * 16 + (lane & 15);
          ls[row * 128 + (col ^ ((row & 7) << 2))] = acc[m][n][j];
        }
    // per-lane trig for i = lane&31 (block-uniform theta set; 1 sincosf)
    const float fme = __expf(-(float)(lane & 31) * (9.2103403720f / 31.0f));
    float snm, csm;
    sincosf((float)ylocal * fme, &snm, &csm);
    __syncthreads();
    const int r     = tid >> 1;              // token row within tile
    const int halfc = tid & 1;               // 0: dims 0..63, 1: dims 64..127
    const int sw    = (r & 7) << 2;
    ushort_t* dstp = Kb + (size_t)(blockIdx.x * 128 + r) * 512
                        + ylocal * 128 + halfc * 64;
    union { ushort_t us[64]; bf16x8 v8[8]; } outv;
    #pragma unroll
    for (int k4 = 0; k4 < 16; ++k4) {
      const int c0 = k4 * 4;                 // local col within this half
      const float4 xa = *(const float4*)&ls[r * 128 + ((halfc * 64 + c0) ^ sw)];
      if (c0 < 32) {
        const float4 xb = *(const float4*)&ls[r * 128 + (((halfc ^ 1) * 64 + c0) ^ sw)];
        #pragma unroll
        for (int e = 0; e < 4; ++e) {
          const float cs = __shfl(csm, c0 + e);   // const idx -> readlane bcast
          const float sn = __shfl(snm, c0 + e);
          const float x1 = halfc ? ((const float*)&xb)[e] : ((const float*)&xa)[e];
          const float x2 = halfc ? ((const float*)&xa)[e] : ((const float*)&xb)[e];
          outv.us[c0 + e] = f2bf(halfc ? (-x1 * sn + x2 * cs)
                                       : ( x1 * cs + x2 * sn));
        }
      } else {
        #pragma unroll
        for (int e = 0; e < 4; ++e)
          outv.us[c0 + e] = f2bf(((const float*)&xa)[e]);
      }
    }
    #pragma unroll
    for (int k8 = 0; k8 < 8; ++k8)
      *(bf16x8*)(dstp + k8 * 8) = outv.v8[k8];
    return;
  }

  const int row0 = blockIdx.x * 128 + wr * 64;
  const int col0 = ylocal * 128 + wc * 64;
  #pragma unroll
  for (int m = 0; m < 4; ++m) {
    #pragma unroll
    for (int n = 0; n < 4; ++n) {
      #pragma unroll
      for (int j = 0; j < 4; ++j) {
        const int gm = row0 + m * 16 + ((lane >> 4) << 2) + j;
        const int gn = col0 + n * 16 + (lane & 15);
        const float v = acc[m][n][j];
        if (mode == 0) {
          Qb[(size_t)gm * 2048 + gn] = f2bf(v);
        } else {
          const int bb = gm >> 11, t2 = gm & 2047;
          Vtb[(size_t)bb * 512 * 2048 + (size_t)gn * 2048 + t2] = f2bf(v);
        }
      }
    }
  }
}

// ---------------------------------------------------------------- GEMM  C = A * B^T
// (out-projection; T3 minimal 2-phase structure, BK=64)
template<int WMODE>
__global__ __launch_bounds__(256, 2)
void gemm_bt(const ushort_t* __restrict__ A, const ushort_t* __restrict__ B,
             void* __restrict__ Cout, int M, int N, int K) {
  __shared__ bf16x8 smem_v[4096];            // 64 KB
  char* smem = (char*)smem_v;
  const int tid  = threadIdx.x;
  const int lane = tid & 63;
  const int wave = tid >> 6;
  const int wr = wave >> 1, wc = wave & 1;
  const ushort_t* Abase = A + (size_t)blockIdx.x * 128 * K;
  const ushort_t* Bbase = B + (size_t)blockIdx.y * 128 * K;

  f32x4 acc[4][4] = {};
  const int nk = K >> 6;

  #pragma unroll
  for (int it = 0; it < 4; ++it) {
    const int chunk = it * 4 + wave;
    const int r  = chunk * 8 + (lane >> 3);
    const int cg = (lane & 7) ^ (r & 7);
    gload_lds16(Abase + (size_t)r * K + cg * 8, smem + chunk * 1024);
    gload_lds16(Bbase + (size_t)r * K + cg * 8, smem + 16384 + chunk * 1024);
  }
  __syncthreads();

  for (int t = 0; t < nk; ++t) {
    if (t + 1 < nk) {
      char* dst = smem + ((t + 1) & 1) * 32768;
      const int k0 = (t + 1) * 64;
      #pragma unroll
      for (int it = 0; it < 4; ++it) {
        const int chunk = it * 4 + wave;
        const int r  = chunk * 8 + (lane >> 3);
        const int cg = (lane & 7) ^ (r & 7);
        gload_lds16(Abase + (size_t)r * K + k0 + cg * 8, dst + chunk * 1024);
        gload_lds16(Bbase + (size_t)r * K + k0 + cg * 8, dst + 16384 + chunk * 1024);
      }
    }

    char* As = smem + (t & 1) * 32768;
    char* Bs = As + 16384;
    bf16x8 af[2][4], bf_[2][4];
    #pragma unroll
    for (int kki = 0; kki < 2; ++kki) {
      #pragma unroll
      for (int m = 0; m < 4; ++m) {
        const int row = wr * 64 + m * 16 + (lane & 15);
        const int cg  = ((kki << 2) + (lane >> 4)) ^ (row & 7);
        af[kki][m] = *(const bf16x8*)(As + row * 128 + cg * 16);
      }
      #pragma unroll
      for (int n = 0; n < 4; ++n) {
        const int row = wc * 64 + n * 16 + (lane & 15);
        const int cg  = ((kki << 2) + (lane >> 4)) ^ (row & 7);
        bf_[kki][n] = *(const bf16x8*)(Bs + row * 128 + cg * 16);
      }
    }
    #pragma unroll
    for (int kki = 0; kki < 2; ++kki)
      #pragma unroll
      for (int m = 0; m < 4; ++m)
        #pragma unroll
        for (int n = 0; n < 4; ++n)
          acc[m][n] = MFMA_BF16(af[kki][m], bf_[kki][n], acc[m][n]);

    __syncthreads();
  }

  const int row0 = blockIdx.x * 128 + wr * 64;
  const int col0 = blockIdx.y * 128 + wc * 64;
  #pragma unroll
  for (int m = 0; m < 4; ++m) {
    #pragma unroll
    for (int n = 0; n < 4; ++n) {
      #pragma unroll
      for (int j = 0; j < 4; ++j) {
        const int gm = row0 + m * 16 + ((lane >> 4) << 2) + j;
        const int gn = col0 + n * 16 + (lane & 15);
        const float v = acc[m][n][j];
        if (WMODE == 0) {
          ((ushort_t*)Cout)[(size_t)gm * N + gn] = f2bf(v);
        } else if (WMODE == 1) {
          ((float*)Cout)[(size_t)gm * N + gn] = v;
        } else {
          const int bb = gm >> 11, t2 = gm & 2047;
          ((ushort_t*)Cout)[(size_t)bb * N * 2048 + (size_t)gn * 2048 + t2] = f2bf(v);
        }
      }
    }
  }
}

// ---------------------------------------------------------------- flash attention
// EXACT r14-verified body (186.6us total; T15 PV-shift REVERTED — r16 isolated
// it as a ~7us regression: pa/vfr live across the barrier -> VGPR 124->128 and
// lost scheduling freedom; wave-level TLP already gave the overlap).
// 4 waves x 32 q-rows, KVBLK=64, swapped QK^T, exp2-domain softmax (__shfl_xor
// reductions), T12 cvt_pk+permlane P-pack, T13 defer-max, fused Q-RoPE,
// vf preload consumed in-iteration, hoisted stage offsets, T1 XCD remap,
// T3 drain0 sync.
__global__ __launch_bounds__(256, 2)
void attn_kernel(const ushort_t* __restrict__ Q, const ushort_t* __restrict__ K,
                 const ushort_t* __restrict__ Vt, ushort_t* __restrict__ AO) {
  __shared__ bf16x8 smem_v[4096];            // 64 KB: 2 x (16KB K + 16KB V^T)
  char* smem = (char*)smem_v;
  const int tid  = threadIdx.x;
  const int lane = tid & 63;
  const int wq   = tid >> 6;
  const int ql   = lane & 31;
  const int hi   = lane >> 5;

  // ---- T1 remap (bijective on 512 blocks; lin%8 = XCD under round-robin);
  //      pairs (lin, lin+256): same (b,h), qt j & 15-j (const 34 tiles/CU pair)
  const int lin = (int)blockIdx.x + 16 * (int)blockIdx.y + 256 * (int)blockIdx.z;
  const int xcd = lin & 7;
  const int s   = lin >> 3;                  // 0..63 within XCD
  const int b   = xcd >> 2;
  const int kh  = xcd & 3;
  const int h   = (kh << 2) + (s & 3);
  const int s4  = s >> 2;                    // 0..15
  const int qt  = (s4 < 8) ? s4 : (23 - s4);

  const int q0b = qt * 128;
  const int qmin_w = q0b + wq * 32;
  const int qmax_w = qmin_w + 31;
  const int qrow = qmin_w + ql;

  const ushort_t* Qp = Q  + (size_t)b * 2048 * 2048 + (size_t)h  * 128;
  const ushort_t* Kp = K  + (size_t)b * 2048 * 512  + (size_t)kh * 128;
  const ushort_t* Vp = Vt + (size_t)b * 512 * 2048  + (size_t)kh * 128 * 2048;

  const int ntiles = (qt + 1) * 2;

  // ---- hoisted per-lane stage offsets (elements / LDS bytes), loop-invariant
  int offK[4], offV[4], ldK[4], ldV[4];
  #pragma unroll
  for (int it = 0; it < 4; ++it) {
    const int ck = it * 4 + wq;
    const int rK = ck * 4 + (lane >> 4);
    const int gK = (lane & 15) ^ (rK & 7);
    offK[it] = rK * 512 + gK * 8;  ldK[it] = ck * 1024;
    const int rV = ck * 8 + (lane >> 3);
    const int gV = (lane & 7) ^ (rV & 7);
    offV[it] = rV * 2048 + gV * 8; ldV[it] = 16384 + ck * 1024;
  }

  // ---- stage tile 0 into buffer 0 (hides under Q-load + RoPE)
  #pragma unroll
  for (int it = 0; it < 4; ++it) {
    gload_lds16(Kp + offK[it], smem + ldK[it]);
    gload_lds16(Vp + offV[it], smem + ldV[it]);
  }

  // ---- load Q fragments + fused head-indexed RoPE, with scale*log2e folded
  const float SCL = 0.08838834764831845f * 1.4426950408889634f;
  bf16x8 qf[8];
  #pragma unroll
  for (int ks = 0; ks < 8; ++ks)
    qf[ks] = *(const bf16x8*)(Qp + (size_t)qrow * 2048 + ks * 16 + hi * 8);
  #pragma unroll
  for (int ks = 0; ks < 2; ++ks) {           // rotated pairs: cols [0,32)+[64,96)
    union { bf16x8 v; ushort_t us[8]; } X1, X2;
    X1.v = qf[ks]; X2.v = qf[ks + 4];
    #pragma unroll
    for (int e = 0; e < 8; ++e) {
      const int i = ks * 16 + hi * 8 + e;
      const float f = __expf(-(float)i * (9.2103403720f / 31.0f));  // 10000^(-i/31)
      float sn, cs;
      sincosf((float)h * f, &sn, &cs);
      const float x1 = bf2f(X1.us[e]), x2 = bf2f(X2.us[e]);
      X1.us[e] = f2bf((x1 * cs + x2 * sn) * SCL);
      X2.us[e] = f2bf((-x1 * sn + x2 * cs) * SCL);
    }
    qf[ks] = X1.v; qf[ks + 4] = X2.v;
  }
  #pragma unroll
  for (int ks = 2; ks < 4; ++ks) {           // unrotated: cols [32,64)+[96,128)
    union { bf16x8 v; ushort_t us[8]; } X1, X2;
    X1.v = qf[ks]; X2.v = qf[ks + 4];
    #pragma unroll
    for (int e = 0; e < 8; ++e) {
      X1.us[e] = f2bf(bf2f(X1.us[e]) * SCL);
      X2.us[e] = f2bf(bf2f(X2.us[e]) * SCL);
    }
    qf[ks] = X1.v; qf[ks + 4] = X2.v;
  }

  float m_ = -3.0e38f, l_ = 0.f;
  f32x16 oacc[4] = {};

  __syncthreads();                           // tile 0 landed (full drain)

  for (int ti = 0; ti < ntiles; ++ti) {
    const int kv0 = ti * 64;
    if (ti + 1 < ntiles) {                   // issue next-tile stage first
      const ushort_t* Kt = Kp + (size_t)(kv0 + 64) * 512;   // uniform advance
      const ushort_t* Vn = Vp + (kv0 + 64);
      char* dst = smem + ((ti + 1) & 1) * 32768;
      #pragma unroll
      for (int it = 0; it < 4; ++it) {
        gload_lds16(Kt + offK[it], dst + ldK[it]);
        gload_lds16(Vn + offV[it], dst + ldV[it]);
      }
    }

    char* Ks = smem + (ti & 1) * 32768;
    char* Vs = Ks + 16384;
    if (kv0 <= qmax_w) {                     // wave-uniform activity gate
      // ---- QK^T (swapped): lane holds S^T[key][q=ql], pre-scaled (log2)
      f32x16 sacc[2] = {};
      __builtin_amdgcn_s_setprio(1);
      #pragma unroll
      for (int kg = 0; kg < 2; ++kg) {
        const int key = kg * 32 + ql;
        #pragma unroll
        for (int ks = 0; ks < 8; ++ks) {
          const int g = ((ks << 1) + hi) ^ (key & 7);
          const bf16x8 kf = *(const bf16x8*)(Ks + key * 256 + g * 16);
          sacc[kg] = MFMA32_BF16(kf, qf[ks], sacc[kg]);
        }
      }
      __builtin_amdgcn_s_setprio(0);

      // ---- vf preload: PV's 16 V-fragments into registers NOW, so the
      //      ds_reads overlap the softmax VALU below (static indexing)
      bf16x8 vfr[4][4];
      #pragma unroll
      for (int dg = 0; dg < 4; ++dg) {
        const int d = dg * 32 + ql;
        #pragma unroll
        for (int ks = 0; ks < 4; ++ks) {
          const int g = ((ks << 1) + hi) ^ (d & 7);
          vfr[dg][ks] = *(const bf16x8*)(Vs + d * 128 + g * 16);
        }
      }

      // ---- causal mask (diagonal tiles only)
      if (kv0 + 63 > qmin_w) {
        #pragma unroll
        for (int kg = 0; kg < 2; ++kg)
          #pragma unroll
          for (int r = 0; r < 16; ++r) {
            const int keyg = kv0 + kg * 32 + (r & 3) + 8 * (r >> 2) + 4 * hi;
            if (keyg > qrow) sacc[kg][r] = -3.0e38f;
          }
      }

      // ---- online softmax, log2 domain (T13 defer-max, THR ~ 8*log2e)
      float mx[8];
      #pragma unroll
      for (int i = 0; i < 8; ++i) {          // depth-3 tree over 32 values
        const int kg = i >> 2, base = (i & 3) * 4;
        mx[i] = fmaxf(fmaxf(sacc[kg][base], sacc[kg][base + 1]),
                      fmaxf(sacc[kg][base + 2], sacc[kg][base + 3]));
      }
      float pm = fmaxf(fmaxf(fmaxf(mx[0], mx[1]), fmaxf(mx[2], mx[3])),
                       fmaxf(fmaxf(mx[4], mx[5]), fmaxf(mx[6], mx[7])));
      pm = fmaxf(pm, __shfl_xor(pm, 32));

      if (__any(pm > m_ + 11.0f)) {
        const float mn = fmaxf(m_, pm);
        const float alpha = exp2_fast(m_ - mn);
        m_ = mn;
        l_ *= alpha;
        #pragma unroll
        for (int r = 0; r < 16; ++r) {
          const float ar = __shfl(alpha, (r & 3) + 8 * (r >> 2) + 4 * hi);
          #pragma unroll
          for (int dg = 0; dg < 4; ++dg) oacc[dg][r] *= ar;
        }
      }

      float rs0 = 0.f, rs1 = 0.f, rs2 = 0.f, rs3 = 0.f;  // 4 parallel chains
      #pragma unroll
      for (int kg = 0; kg < 2; ++kg)
        #pragma unroll
        for (int r = 0; r < 16; r += 4) {
          const float p0 = exp2_fast(sacc[kg][r]     - m_);
          const float p1 = exp2_fast(sacc[kg][r + 1] - m_);
          const float p2 = exp2_fast(sacc[kg][r + 2] - m_);
          const float p3 = exp2_fast(sacc[kg][r + 3] - m_);
          sacc[kg][r] = p0; sacc[kg][r + 1] = p1;
          sacc[kg][r + 2] = p2; sacc[kg][r + 3] = p3;
          rs0 += p0; rs1 += p1; rs2 += p2; rs3 += p3;
        }
      float rs = (rs0 + rs1) + (rs2 + rs3);
      rs += __shfl_xor(rs, 32);
      l_ += rs;

      // ---- P -> A-fragments via v_cvt_pk_bf16_f32 + permlane32_swap (T12)
      bf16x8 pa[4];
      #pragma unroll
      for (int ks = 0; ks < 4; ++ks) {
        const int kg = ks >> 1;
        const int base = 8 * (ks & 1);
        union { uint32_t w[4]; bf16x8 v; } U;
        #pragma unroll
        for (int j = 0; j < 2; ++j) {
          uint32_t a  = cvtpk_bf16(sacc[kg][base + 2 * j],     sacc[kg][base + 2 * j + 1]);
          uint32_t bb = cvtpk_bf16(sacc[kg][base + 4 + 2 * j], sacc[kg][base + 4 + 2 * j + 1]);
          asm volatile("v_permlane32_swap_b32 %0, %1" : "+v"(a), "+v"(bb));
          U.w[j] = a; U.w[2 + j] = bb;
        }
        pa[ks] = U.v;
      }

      // ---- O += P V   (V fragments already in registers)
      __builtin_amdgcn_s_setprio(1);
      #pragma unroll
      for (int dg = 0; dg < 4; ++dg)
        #pragma unroll
        for (int ks = 0; ks < 4; ++ks)
          oacc[dg] = MFMA32_BF16(pa[ks], vfr[dg][ks], oacc[dg]);
      __builtin_amdgcn_s_setprio(0);
    }

    __syncthreads();   // drains: stage(ti+1) landed; all waves done with buf
  }

  // ---- epilogue: normalize, store bf16
  const float linv = 1.0f / l_;
  ushort_t* AOp = AO + (size_t)b * 2048 * 2048 + (size_t)h * 128;
  #pragma unroll
  for (int r = 0; r < 16; ++r) {
    const int cr = (r & 3) + 8 * (r >> 2) + 4 * hi;
    const float li = __shfl(linv, cr);
    const int row = q0b + wq * 32 + cr;
    #pragma unroll
    for (int dg = 0; dg < 4; ++dg)
      AOp[(size_t)row * 2048 + dg * 32 + ql] = f2bf(oacc[dg][r] * li);
  }
}

// ---------------------------------------------------------------- launch
extern "C" void kernel_launch(void* const* d_in, const int* in_sizes, int n_in,
                              void* d_out, int out_size, void* d_ws, size_t ws_size,
                              hipStream_t stream) {
  const float* x  = (const float*)d_in[0];
  const float* wq = (const float*)d_in[1];
  const float* wk = (const float*)d_in[2];
  const float* wv = (const float*)d_in[3];
  const float* wo = (const float*)d_in[4];
  float* out = (float*)d_out;
  char* ws = (char*)d_ws;

  ushort_t* xb  = (ushort_t*)(ws);               // x   bf16  4096x2048
  ushort_t* wqb = (ushort_t*)(ws + 16777216);    // wq  bf16  2048x2048
  ushort_t* wkb = (ushort_t*)(ws + 25165824);    // wk  bf16   512x2048
  ushort_t* wvb = (ushort_t*)(ws + 27262976);    // wv  bf16   512x2048
  ushort_t* wob = (ushort_t*)(ws + 29360128);    // wo  bf16  2048x2048
  ushort_t* Qb  = (ushort_t*)(ws + 37748736);    // Q   bf16  4096x2048 (pre-RoPE)
  ushort_t* Kb  = (ushort_t*)(ws + 54525952);    // K   bf16  4096x512  (RoPE'd in GEMM)
  ushort_t* Vtb = (ushort_t*)(ws + 58720256);    // V^T bf16  [2][512][2048]
  ushort_t* AOb = (ushort_t*)(ws + 62914560);    // attn out bf16 4096x2048

  cvt_kernel<<<dim3(8192, 5), 256, 0, stream>>>(x, wq, wk, wv, wo,
                                                xb, wqb, wkb, wvb, wob);
  gemm_qkv<<<dim3(32, 24), 256, 0, stream>>>(xb, wqb, wkb, wvb, Qb, Kb, Vtb);
  attn_kernel<<<dim3(16, 16, 2), 256, 0, stream>>>(Qb, Kb, Vtb, AOb);
  gemm_bt<1><<<dim3(32, 16), 256, 0, stream>>>(AOb, wob, out, 4096, 2048, 2048);
}